// Round 5
// baseline (537.425 us; speedup 1.0000x reference)
//
#include <hip/hip_runtime.h>
#include <hip/hip_cooperative_groups.h>
#include <math.h>

namespace cg = cooperative_groups;

#define NUM_CODE 20000
#define EMBED_D  256
#define HID      128
#define CC       64
#define NBV      3200
#define NTILE    (NUM_CODE / 16)   // 1250 16-row score tiles

typedef __attribute__((ext_vector_type(8))) short bf16x8;
typedef __attribute__((ext_vector_type(4))) float f32x4;

__device__ __forceinline__ unsigned f2bf1(float f) {
    union { float f; unsigned u; } c; c.f = f;
    return (c.u + 0x7FFFu + ((c.u >> 16) & 1u)) >> 16;   // RNE
}
__device__ __forceinline__ unsigned pk2(float lo, float hi) {
    return f2bf1(lo) | (f2bf1(hi) << 16);
}
__device__ __forceinline__ float bflo(unsigned u) {
    union { unsigned u; float f; } c; c.u = u << 16; return c.f;
}
__device__ __forceinline__ float bfhi(unsigned u) {
    union { unsigned u; float f; } c; c.u = u & 0xFFFF0000u; return c.f;
}

// ---------------- Phase 0: W1 f32 -> bf16 (row-major) ----------------------
__device__ __forceinline__ void phase_w1(const float* __restrict__ W1,
                                         unsigned short* __restrict__ W1b,
                                         int nblocks)
{
    for (int f = blockIdx.x * 256 + threadIdx.x; f < HID * EMBED_D / 4;
         f += nblocks * 256) {
        float4 v = ((const float4*)W1)[f];
        uint2 o; o.x = pk2(v.x, v.y); o.y = pk2(v.z, v.w);
        ((uint2*)W1b)[f] = o;
    }
}

// ---------------- Phase 1: scores via MFMA, full-N per wave ----------------
// Wave handles 16 rows, all 8 n-tiles, K=256 in 8 steps with 4-deep A
// prefetch. A frag: row=l&15, k=(l>>4)*8 (+32*s). Fused bf16 table writeout.
// C layout (m89-verified): m=(l>>4)*4+r, n=l&15.
__device__ __forceinline__ void phase_score(
    const float* __restrict__ table, const unsigned short* __restrict__ W1b,
    const float* __restrict__ b1, const float* __restrict__ W2,
    const float* __restrict__ b2, float* __restrict__ scores,
    unsigned short* __restrict__ tbl_bf, int nblocks)
{
    const int l   = threadIdx.x & 63;
    const int w   = threadIdx.x >> 6;
    const int row = l & 15;
    const int kg  = l >> 4;
    const int nw  = nblocks * 4;

    for (int t = w * nblocks + blockIdx.x; t < NTILE; t += nw) {
        const int m0 = t * 16;
        const float* arow = table + (size_t)(m0 + row) * EMBED_D + kg * 8;

        f32x4 acc[8];
#pragma unroll
        for (int j = 0; j < 8; j++) acc[j] = (f32x4){0.f, 0.f, 0.f, 0.f};

        float4 a[4][2];
#pragma unroll
        for (int s = 0; s < 4; s++) {
            a[s][0] = *(const float4*)(arow + s * 32);
            a[s][1] = *(const float4*)(arow + s * 32 + 4);
        }
#pragma unroll
        for (int s = 0; s < 8; s++) {
            float4 x0 = a[s & 3][0], x1 = a[s & 3][1];
            if (s + 4 < 8) {
                a[s & 3][0] = *(const float4*)(arow + (s + 4) * 32);
                a[s & 3][1] = *(const float4*)(arow + (s + 4) * 32 + 4);
            }
            union { uint4 u; bf16x8 v; } p;
            p.u.x = pk2(x0.x, x0.y); p.u.y = pk2(x0.z, x0.w);
            p.u.z = pk2(x1.x, x1.y); p.u.w = pk2(x1.z, x1.w);
            *(uint4*)(tbl_bf + (size_t)(m0 + row) * EMBED_D + s * 32 + kg * 8) = p.u;
#pragma unroll
            for (int j = 0; j < 8; j++) {
                bf16x8 bf = *(const bf16x8*)(W1b + (size_t)(j * 16 + row) * EMBED_D + s * 32 + kg * 8);
                acc[j] = __builtin_amdgcn_mfma_f32_16x16x32_bf16(p.v, bf, acc[j], 0, 0, 0);
            }
        }

        float w2v[8], b1v[8];
#pragma unroll
        for (int j = 0; j < 8; j++) {
            w2v[j] = W2[j * 16 + row];
            b1v[j] = b1[j * 16 + row];
        }
#pragma unroll
        for (int r = 0; r < 4; r++) {
            float part = 0.f;
#pragma unroll
            for (int j = 0; j < 8; j++)
                part += w2v[j] * tanhf(acc[j][r] + b1v[j]);
#pragma unroll
            for (int o = 1; o < 16; o <<= 1)
                part += __shfl_xor(part, o, 16);
            if (row == 0)
                scores[m0 + kg * 4 + r] = part + b2[0];
        }
    }
}

// ---------------- Phase 2: masked softmax + weighted gather-sum ------------
__device__ __forceinline__ void phase_attn(
    const int* __restrict__ codes, const int* __restrict__ lens,
    const uint4* __restrict__ t16, const float* __restrict__ scores,
    float* __restrict__ out, float* attn_s, int* code_s,
    float (*red)[256], int nblocks)
{
    const int tid = threadIdx.x;
    const int g   = tid >> 5;
    const int l   = tid & 31;

    for (int bv = blockIdx.x; bv < NBV; bv += nblocks) {
        int c_reg = 0;
        if (tid < CC) {
            c_reg = codes[(size_t)bv * CC + tid];
            code_s[tid] = c_reg;
        }
        __syncthreads();

        uint4 v[8];
#pragma unroll
        for (int cc = 0; cc < 8; cc++)
            v[cc] = t16[(size_t)code_s[cc * 8 + g] * 32 + l];

        if (tid < CC) {
            float sc  = scores[c_reg];
            int   len = lens[bv];
            float val = (tid < len) ? sc : -1e9f;
            float m = val;
#pragma unroll
            for (int o = 32; o >= 1; o >>= 1)
                m = fmaxf(m, __shfl_xor(m, o, 64));
            float e = expf(val - m);
            float sum = e;
#pragma unroll
            for (int o = 32; o >= 1; o >>= 1)
                sum += __shfl_xor(sum, o, 64);
            attn_s[tid] = e / sum;
        }
        __syncthreads();

        float acc[8] = {0.f, 0.f, 0.f, 0.f, 0.f, 0.f, 0.f, 0.f};
#pragma unroll
        for (int cc = 0; cc < 8; cc++) {
            float a = attn_s[cc * 8 + g];
            unsigned u;
            u = v[cc].x; acc[0] += a * bflo(u); acc[1] += a * bfhi(u);
            u = v[cc].y; acc[2] += a * bflo(u); acc[3] += a * bfhi(u);
            u = v[cc].z; acc[4] += a * bflo(u); acc[5] += a * bfhi(u);
            u = v[cc].w; acc[6] += a * bflo(u); acc[7] += a * bfhi(u);
        }
        *(float4*)&red[g][l * 8]     = make_float4(acc[0], acc[1], acc[2], acc[3]);
        *(float4*)&red[g][l * 8 + 4] = make_float4(acc[4], acc[5], acc[6], acc[7]);
        __syncthreads();

        if (tid < 64) {
            float4 o = make_float4(0.f, 0.f, 0.f, 0.f);
#pragma unroll
            for (int g2 = 0; g2 < 8; g2++) {
                float4 r = *(const float4*)&red[g2][tid * 4];
                o.x += r.x; o.y += r.y; o.z += r.z; o.w += r.w;
            }
            ((float4*)out)[(size_t)bv * 64 + tid] = o;
        }
        __syncthreads();   // LDS safe for next grid-stride iteration
    }
}

// ---------------- Cooperative fused kernel ---------------------------------
#define COOP_GRID 1024

__global__ __launch_bounds__(256, 4) void coop_all(
    const float* __restrict__ table, const int* __restrict__ codes,
    const int* __restrict__ lens, const float* __restrict__ W1,
    const float* __restrict__ b1, const float* __restrict__ W2,
    const float* __restrict__ b2, float* __restrict__ scores,
    unsigned short* __restrict__ W1b, unsigned short* __restrict__ tbl_bf,
    float* __restrict__ out)
{
    __shared__ float attn_s[CC];
    __shared__ int   code_s[CC];
    __shared__ float red[8][256];

    cg::grid_group grid = cg::this_grid();

    phase_w1(W1, W1b, COOP_GRID);
    __threadfence();
    grid.sync();
    phase_score(table, W1b, b1, W2, b2, scores, tbl_bf, COOP_GRID);
    __threadfence();
    grid.sync();
    phase_attn(codes, lens, (const uint4*)tbl_bf, scores, out,
               attn_s, code_s, red, COOP_GRID);
}

// ---------------- Standalone fallbacks (no grid.sync) ----------------------
__global__ __launch_bounds__(256) void k_w1(
    const float* __restrict__ W1, unsigned short* __restrict__ W1b)
{
    phase_w1(W1, W1b, 32);
}

__global__ __launch_bounds__(256) void k_score(
    const float* __restrict__ table, const unsigned short* __restrict__ W1b,
    const float* __restrict__ b1, const float* __restrict__ W2,
    const float* __restrict__ b2, float* __restrict__ scores,
    unsigned short* __restrict__ tbl_bf)
{
    phase_score(table, W1b, b1, W2, b2, scores, tbl_bf, 313);
}

__global__ __launch_bounds__(256) void k_attn(
    const int* __restrict__ codes, const int* __restrict__ lens,
    const uint4* __restrict__ t16, const float* __restrict__ scores,
    float* __restrict__ out)
{
    __shared__ float attn_s[CC];
    __shared__ int   code_s[CC];
    __shared__ float red[8][256];
    phase_attn(codes, lens, t16, scores, out, attn_s, code_s, red, NBV);
}

extern "C" void kernel_launch(void* const* d_in, const int* in_sizes, int n_in,
                              void* d_out, int out_size, void* d_ws, size_t ws_size,
                              hipStream_t stream) {
    const float* table = (const float*)d_in[2]; // [20000,256]
    const int*   codes = (const int*)d_in[0];   // [64,50,64]
    const int*   lens  = (const int*)d_in[1];   // [64,50]
    const float* W1 = (const float*)d_in[3];
    const float* b1 = (const float*)d_in[4];
    const float* W2 = (const float*)d_in[5];
    const float* b2 = (const float*)d_in[6];
    float* out = (float*)d_out;

    // ws layout: scores (80 KB) | W1b (64 KB) | tbl_bf (10.24 MB)
    float*          scores = (float*)d_ws;
    unsigned short* W1b    = (unsigned short*)((char*)d_ws + 81920);
    unsigned short* tbl_bf = (unsigned short*)((char*)d_ws + 81920 + 65536);
    const size_t need = 81920 + 65536 + (size_t)NUM_CODE * EMBED_D * 2;

    if (ws_size >= need) {
        void* args[] = {
            (void*)&table, (void*)&codes, (void*)&lens, (void*)&W1,
            (void*)&b1, (void*)&W2, (void*)&b2, (void*)&scores,
            (void*)&W1b, (void*)&tbl_bf, (void*)&out
        };
        hipError_t e = hipLaunchCooperativeKernel(
            (const void*)coop_all, dim3(COOP_GRID), dim3(256), args, 0, stream);
        if (e == hipSuccess) return;
        // fall through to split path on any cooperative-launch failure
        k_w1<<<32, 256, 0, stream>>>(W1, W1b);
        k_score<<<313, 256, 0, stream>>>(table, W1b, b1, W2, b2, scores, tbl_bf);
        k_attn<<<NBV, 256, 0, stream>>>(codes, lens, (const uint4*)tbl_bf,
                                        scores, out);
    }
    // (ws_size is 268 MB in this harness; the need check never fails in
    // practice, but if it did we would have no tbl_bf — handle by running
    // the split path writing bf16 into the scores tail is impossible, so
    // just run coop path requirements-free fallback: reuse f32 table via
    // the same kernels is omitted — ws_size >> need always holds.)
}

// Round 6
// 195.673 us; speedup vs baseline: 2.7465x; 2.7465x over previous
//
#include <hip/hip_runtime.h>
#include <math.h>

#define NUM_CODE 20000
#define EMBED_D  256
#define HID      128
#define CC       64
#define NBV      3200

typedef __attribute__((ext_vector_type(8))) short bf16x8;
typedef __attribute__((ext_vector_type(4))) float f32x4;

__device__ __forceinline__ unsigned f2bf1(float f) {
    union { float f; unsigned u; } c; c.f = f;
    return (c.u + 0x7FFFu + ((c.u >> 16) & 1u)) >> 16;   // RNE
}
__device__ __forceinline__ unsigned pk2(float lo, float hi) {
    return f2bf1(lo) | (f2bf1(hi) << 16);
}
__device__ __forceinline__ float bflo(unsigned u) {
    union { unsigned u; float f; } c; c.u = u << 16; return c.f;
}
__device__ __forceinline__ float bfhi(unsigned u) {
    union { unsigned u; float f; } c; c.u = u & 0xFFFF0000u; return c.f;
}
__device__ __forceinline__ float tanh_fast(float x) {
    // tanh(x) = 1 - 2/(1+e^{2x}); overflow->inf->1, underflow->0->-1 : correct
    float t = __expf(2.0f * x);
    return 1.0f - 2.0f / (1.0f + t);
}

// ---------------------------------------------------------------------------
// Kernel 0: stream-convert table f32[20000][256] and W1 f32[128][256] to bf16.
// Grid 5032 x 256: blocks 0..4999 -> table (1 float4/thread), 5000.. -> W1.
// ---------------------------------------------------------------------------
__global__ __launch_bounds__(256) void cvt_kernel(
    const float* __restrict__ table, const float* __restrict__ W1,
    unsigned short* __restrict__ tbl_bf, unsigned short* __restrict__ W1b)
{
    int b = blockIdx.x;
    if (b < 5000) {
        int f = b * 256 + threadIdx.x;            // 1,280,000 float4 total
        float4 v = ((const float4*)table)[f];
        uint2 o; o.x = pk2(v.x, v.y); o.y = pk2(v.z, v.w);
        ((uint2*)tbl_bf)[f] = o;
    } else {
        int f = (b - 5000) * 256 + threadIdx.x;   // 8,192 float4 of W1
        float4 v = ((const float4*)W1)[f];
        uint2 o; o.x = pk2(v.x, v.y); o.y = pk2(v.z, v.w);
        ((uint2*)W1b)[f] = o;
    }
}

// ---------------------------------------------------------------------------
// Kernel 1: fused per-(b,v) block. 3200 blocks x 256 threads (4 waves).
// Phase 1: gather 64 bf16 rows (8 x uint4/thread, held in registers).
// Phase 2: stage emb to LDS [64][264] bf16 (+8 pad -> ~2-way banks).
// Phase 3: per-wave MFMA GEMM H=emb@W1^T (rows 16w..16w+15, all 128 hid).
// Phase 4: tanh+W2-dot epilogue -> per-code score (b2 dropped: softmax-shift-
//          invariant), 16-lane reduce -> wrow[64].
// Phase 5: masked softmax over 64 (wave 0).
// Phase 6: PV from REGISTERS (v[] still live) -> LDS reduce (red aliases emb,
//          which is dead after phase 3) -> out.
// A/B/C frag layout identical to the R2-R5 verified score kernel.
// ---------------------------------------------------------------------------
__global__ __launch_bounds__(256, 4) void fused_kernel(
    const int* __restrict__ codes, const int* __restrict__ lens,
    const uint4* __restrict__ t16, const unsigned short* __restrict__ W1b,
    const float* __restrict__ b1, const float* __restrict__ W2,
    float* __restrict__ out)
{
    __shared__ uint4 smem4[2112];            // 33792 B: emb, later red
    __shared__ int   code_s[CC];
    __shared__ float wrow[CC];
    __shared__ float attn_s[CC];

    unsigned short* emb = (unsigned short*)smem4;   // [64][264] bf16
    float*          red = (float*)smem4;            // [8][256] f32 (aliased)

    const int bv  = blockIdx.x;
    const int tid = threadIdx.x;
    const int g   = tid >> 5;     // gather group 0..7
    const int l   = tid & 31;     // 16B chunk index within row
    const int l6  = tid & 63;
    const int w   = tid >> 6;     // wave 0..3
    const int row = l6 & 15;
    const int kg  = l6 >> 4;

    if (tid < CC) code_s[tid] = codes[(size_t)bv * CC + tid];
    __syncthreads();

    // Phase 1: gather (issued first; latency hides under everything below)
    uint4 v[8];
#pragma unroll
    for (int cc = 0; cc < 8; cc++)
        v[cc] = t16[(size_t)code_s[cc * 8 + g] * 32 + l];

    // Phase 2: stage to LDS (dims 8l..8l+7 of row cc*8+g)
#pragma unroll
    for (int cc = 0; cc < 8; cc++) {
        int c = cc * 8 + g;
        *(uint4*)&emb[c * 264 + l * 8] = v[cc];
    }
    __syncthreads();

    // Phase 3: GEMM
    f32x4 acc[8];
#pragma unroll
    for (int j = 0; j < 8; j++) acc[j] = (f32x4){0.f, 0.f, 0.f, 0.f};
#pragma unroll
    for (int s = 0; s < 8; s++) {
        bf16x8 afrag = *(const bf16x8*)&emb[(16 * w + row) * 264 + s * 32 + kg * 8];
#pragma unroll
        for (int j = 0; j < 8; j++) {
            bf16x8 bw = *(const bf16x8*)&W1b[(size_t)(j * 16 + row) * EMBED_D + s * 32 + kg * 8];
            acc[j] = __builtin_amdgcn_mfma_f32_16x16x32_bf16(afrag, bw, acc[j], 0, 0, 0);
        }
    }

    // Phase 4: epilogue -> wrow
    float part[4] = {0.f, 0.f, 0.f, 0.f};
#pragma unroll
    for (int j = 0; j < 8; j++) {
        float w2 = W2[j * 16 + row];
        float bb = b1[j * 16 + row];
#pragma unroll
        for (int r = 0; r < 4; r++)
            part[r] += w2 * tanh_fast(acc[j][r] + bb);
    }
#pragma unroll
    for (int r = 0; r < 4; r++) {
#pragma unroll
        for (int o = 1; o < 16; o <<= 1)
            part[r] += __shfl_xor(part[r], o, 16);
    }
    if (row == 0) {
#pragma unroll
        for (int r = 0; r < 4; r++)
            wrow[16 * w + kg * 4 + r] = part[r];
    }
    __syncthreads();

    // Phase 5: masked softmax over the 64 codes
    if (tid < CC) {
        int len = lens[bv];
        float val = (tid < len) ? wrow[tid] : -1e9f;
        float m = val;
#pragma unroll
        for (int o = 32; o >= 1; o >>= 1)
            m = fmaxf(m, __shfl_xor(m, o, 64));
        float e = expf(val - m);
        float sum = e;
#pragma unroll
        for (int o = 32; o >= 1; o >>= 1)
            sum += __shfl_xor(sum, o, 64);
        attn_s[tid] = e / sum;
    }
    __syncthreads();

    // Phase 6: PV from registers, reduce via red (aliases emb: safe — last
    // emb read was phase 3, which precedes the phase-4 barrier)
    float a2[8] = {0.f, 0.f, 0.f, 0.f, 0.f, 0.f, 0.f, 0.f};
#pragma unroll
    for (int cc = 0; cc < 8; cc++) {
        float a = attn_s[cc * 8 + g];
        unsigned u;
        u = v[cc].x; a2[0] += a * bflo(u); a2[1] += a * bfhi(u);
        u = v[cc].y; a2[2] += a * bflo(u); a2[3] += a * bfhi(u);
        u = v[cc].z; a2[4] += a * bflo(u); a2[5] += a * bfhi(u);
        u = v[cc].w; a2[6] += a * bflo(u); a2[7] += a * bfhi(u);
    }
    *(float4*)&red[g * 256 + l * 8]     = make_float4(a2[0], a2[1], a2[2], a2[3]);
    *(float4*)&red[g * 256 + l * 8 + 4] = make_float4(a2[4], a2[5], a2[6], a2[7]);
    __syncthreads();

    if (tid < 64) {
        float4 o = make_float4(0.f, 0.f, 0.f, 0.f);
#pragma unroll
        for (int g2 = 0; g2 < 8; g2++) {
            float4 r = *(const float4*)&red[g2 * 256 + tid * 4];
            o.x += r.x; o.y += r.y; o.z += r.z; o.w += r.w;
        }
        ((float4*)out)[(size_t)bv * 64 + tid] = o;
    }
}

extern "C" void kernel_launch(void* const* d_in, const int* in_sizes, int n_in,
                              void* d_out, int out_size, void* d_ws, size_t ws_size,
                              hipStream_t stream) {
    const int*   codes = (const int*)d_in[0];   // [64,50,64]
    const int*   lens  = (const int*)d_in[1];   // [64,50]
    const float* table = (const float*)d_in[2]; // [20000,256]
    const float* W1 = (const float*)d_in[3];    // [128,256]
    const float* b1 = (const float*)d_in[4];    // [128]
    const float* W2 = (const float*)d_in[5];    // [1,128]
    // b2 (d_in[6]) intentionally unused: softmax is shift-invariant.
    float* out = (float*)d_out;                 // [64,50,256]

    // ws: tbl_bf (10.24 MB) | W1b (64 KB)
    unsigned short* tbl_bf = (unsigned short*)d_ws;
    unsigned short* W1b    = (unsigned short*)((char*)d_ws
                              + (size_t)NUM_CODE * EMBED_D * 2);

    cvt_kernel<<<5032, 256, 0, stream>>>(table, W1, tbl_bf, W1b);
    fused_kernel<<<NBV, 256, 0, stream>>>(codes, lens, (const uint4*)tbl_bf,
                                          W1b, b1, W2, out);
}

// Round 7
// 127.672 us; speedup vs baseline: 4.2094x; 1.5326x over previous
//
#include <hip/hip_runtime.h>
#include <math.h>

#define NUM_CODE 20000
#define EMBED_D  256
#define HID      128
#define CC       64
#define NBV      3200

typedef __attribute__((ext_vector_type(8))) short bf16x8;
typedef __attribute__((ext_vector_type(4))) float f32x4;

__device__ __forceinline__ unsigned f2bf1(float f) {
    union { float f; unsigned u; } c; c.f = f;
    return (c.u + 0x7FFFu + ((c.u >> 16) & 1u)) >> 16;   // RNE
}
__device__ __forceinline__ unsigned pk2(float lo, float hi) {
    return f2bf1(lo) | (f2bf1(hi) << 16);
}
__device__ __forceinline__ float bflo(unsigned u) {
    union { unsigned u; float f; } c; c.u = u << 16; return c.f;
}
__device__ __forceinline__ float bfhi(unsigned u) {
    union { unsigned u; float f; } c; c.u = u & 0xFFFF0000u; return c.f;
}
__device__ __forceinline__ float tanh_fast(float x) {
    float t = __expf(2.0f * x);
    return 1.0f - 2.0f / (1.0f + t);
}

// ---------------------------------------------------------------------------
// Kernel 0: stream-convert table and W1 to bf16. Grid 5032 x 256.
// ---------------------------------------------------------------------------
__global__ __launch_bounds__(256) void cvt_kernel(
    const float* __restrict__ table, const float* __restrict__ W1,
    unsigned short* __restrict__ tbl_bf, unsigned short* __restrict__ W1b)
{
    int b = blockIdx.x;
    if (b < 5000) {
        int f = b * 256 + threadIdx.x;
        float4 v = ((const float4*)table)[f];
        uint2 o; o.x = pk2(v.x, v.y); o.y = pk2(v.z, v.w);
        ((uint2*)tbl_bf)[f] = o;
    } else {
        int f = (b - 5000) * 256 + threadIdx.x;
        float4 v = ((const float4*)W1)[f];
        uint2 o; o.x = pk2(v.x, v.y); o.y = pk2(v.z, v.w);
        ((uint2*)W1b)[f] = o;
    }
}

// ---------------------------------------------------------------------------
// Kernel 1: fused per-(b,v) block, j-SPLIT GEMM.
// 4 waves; wave w owns hid-tiles j in {2w, 2w+1}, loops all 4 M-tiles from
// LDS. Per-thread W1b loads: 16 (was 64); block W1b traffic 64 KB (was 256).
// Phases: gather(regs) -> LDS stage -> GEMM(j-split) -> partial epilogue ->
// 4-way LDS combine -> softmax -> PV from regs -> out.
// ---------------------------------------------------------------------------
__global__ __launch_bounds__(256, 4) void fused_kernel(
    const int* __restrict__ codes, const int* __restrict__ lens,
    const uint4* __restrict__ t16, const unsigned short* __restrict__ W1b,
    const float* __restrict__ b1, const float* __restrict__ W2,
    float* __restrict__ out)
{
    __shared__ uint4 smem4[2112];            // 33792 B: emb, later red
    __shared__ int   code_s[CC];
    __shared__ float comb[4][68];            // per-wave partial scores
    __shared__ float attn_s[CC];

    unsigned short* emb = (unsigned short*)smem4;   // [64][264] bf16
    float*          red = (float*)smem4;            // [8][256] f32 (aliased)

    const int bv  = blockIdx.x;
    const int tid = threadIdx.x;
    const int g   = tid >> 5;     // gather group 0..7
    const int l   = tid & 31;     // 16B chunk index within row
    const int l6  = tid & 63;
    const int w   = tid >> 6;     // wave 0..3
    const int row = l6 & 15;
    const int kg  = l6 >> 4;

    if (tid < CC) code_s[tid] = codes[(size_t)bv * CC + tid];
    __syncthreads();

    // Phase 1: gather 64 bf16 rows into registers (8 x uint4/thread)
    uint4 v[8];
#pragma unroll
    for (int cc = 0; cc < 8; cc++)
        v[cc] = t16[(size_t)code_s[cc * 8 + g] * 32 + l];

    // Phase 2: stage to LDS
#pragma unroll
    for (int cc = 0; cc < 8; cc++)
        *(uint4*)&emb[(cc * 8 + g) * 264 + l * 8] = v[cc];
    __syncthreads();

    // Phase 3: j-split GEMM. acc[m][jj] for M-tile m, hid-tile 2w+jj.
    const unsigned short* wb0 = W1b + (size_t)((2 * w) * 16 + row) * EMBED_D;
    const unsigned short* wb1 = wb0 + 16 * EMBED_D;

    f32x4 acc[4][2];
#pragma unroll
    for (int m = 0; m < 4; m++) {
        acc[m][0] = (f32x4){0.f, 0.f, 0.f, 0.f};
        acc[m][1] = (f32x4){0.f, 0.f, 0.f, 0.f};
    }
#pragma unroll
    for (int s = 0; s < 8; s++) {
        bf16x8 bw0 = *(const bf16x8*)(wb0 + s * 32 + kg * 8);
        bf16x8 bw1 = *(const bf16x8*)(wb1 + s * 32 + kg * 8);
#pragma unroll
        for (int m = 0; m < 4; m++) {
            bf16x8 af = *(const bf16x8*)&emb[(16 * m + row) * 264 + s * 32 + kg * 8];
            acc[m][0] = __builtin_amdgcn_mfma_f32_16x16x32_bf16(af, bw0, acc[m][0], 0, 0, 0);
            acc[m][1] = __builtin_amdgcn_mfma_f32_16x16x32_bf16(af, bw1, acc[m][1], 0, 0, 0);
        }
    }

    // Phase 4: partial epilogue. Lane holds H[16m+kg*4+r][(2w+jj)*16+row].
    float w2v[2], b1v[2];
#pragma unroll
    for (int jj = 0; jj < 2; jj++) {
        int n = (2 * w + jj) * 16 + row;
        w2v[jj] = W2[n];
        b1v[jj] = b1[n];
    }
#pragma unroll
    for (int m = 0; m < 4; m++) {
#pragma unroll
        for (int r = 0; r < 4; r++) {
            float part = w2v[0] * tanh_fast(acc[m][0][r] + b1v[0])
                       + w2v[1] * tanh_fast(acc[m][1][r] + b1v[1]);
#pragma unroll
            for (int o = 1; o < 16; o <<= 1)
                part += __shfl_xor(part, o, 16);
            if (row == 0)
                comb[w][16 * m + kg * 4 + r] = part;
        }
    }
    __syncthreads();

    // Phase 5: masked softmax over the 64 codes (b2 dropped: shift-invariant)
    if (tid < CC) {
        int len = lens[bv];
        float sc = comb[0][tid] + comb[1][tid] + comb[2][tid] + comb[3][tid];
        float val = (tid < len) ? sc : -1e9f;
        float m = val;
#pragma unroll
        for (int o = 32; o >= 1; o >>= 1)
            m = fmaxf(m, __shfl_xor(m, o, 64));
        float e = __expf(val - m);
        float sum = e;
#pragma unroll
        for (int o = 32; o >= 1; o >>= 1)
            sum += __shfl_xor(sum, o, 64);
        attn_s[tid] = e / sum;
    }
    __syncthreads();

    // Phase 6: PV from registers; red aliases emb (dead since phase 3's
    // reads, which precede the phase-4 barrier).
    float a2[8] = {0.f, 0.f, 0.f, 0.f, 0.f, 0.f, 0.f, 0.f};
#pragma unroll
    for (int cc = 0; cc < 8; cc++) {
        float a = attn_s[cc * 8 + g];
        unsigned u;
        u = v[cc].x; a2[0] += a * bflo(u); a2[1] += a * bfhi(u);
        u = v[cc].y; a2[2] += a * bflo(u); a2[3] += a * bfhi(u);
        u = v[cc].z; a2[4] += a * bflo(u); a2[5] += a * bfhi(u);
        u = v[cc].w; a2[6] += a * bflo(u); a2[7] += a * bfhi(u);
    }
    *(float4*)&red[g * 256 + l * 8]     = make_float4(a2[0], a2[1], a2[2], a2[3]);
    *(float4*)&red[g * 256 + l * 8 + 4] = make_float4(a2[4], a2[5], a2[6], a2[7]);
    __syncthreads();

    if (tid < 64) {
        float4 o = make_float4(0.f, 0.f, 0.f, 0.f);
#pragma unroll
        for (int g2 = 0; g2 < 8; g2++) {
            float4 r = *(const float4*)&red[g2 * 256 + tid * 4];
            o.x += r.x; o.y += r.y; o.z += r.z; o.w += r.w;
        }
        ((float4*)out)[(size_t)bv * 64 + tid] = o;
    }
}

extern "C" void kernel_launch(void* const* d_in, const int* in_sizes, int n_in,
                              void* d_out, int out_size, void* d_ws, size_t ws_size,
                              hipStream_t stream) {
    const int*   codes = (const int*)d_in[0];   // [64,50,64]
    const int*   lens  = (const int*)d_in[1];   // [64,50]
    const float* table = (const float*)d_in[2]; // [20000,256]
    const float* W1 = (const float*)d_in[3];    // [128,256]
    const float* b1 = (const float*)d_in[4];    // [128]
    const float* W2 = (const float*)d_in[5];    // [1,128]
    // b2 (d_in[6]) unused: softmax is shift-invariant.
    float* out = (float*)d_out;                 // [64,50,256]

    // ws: tbl_bf (10.24 MB) | W1b (64 KB)
    unsigned short* tbl_bf = (unsigned short*)d_ws;
    unsigned short* W1b    = (unsigned short*)((char*)d_ws
                              + (size_t)NUM_CODE * EMBED_D * 2);

    cvt_kernel<<<5032, 256, 0, stream>>>(table, W1, tbl_bf, W1b);
    fused_kernel<<<NBV, 256, 0, stream>>>(codes, lens, (const uint4*)tbl_bf,
                                          W1b, b1, W2, out);
}